// Round 1
// baseline (633.922 us; speedup 1.0000x reference)
//
#include <hip/hip_runtime.h>
#include <cstdio>

typedef __bf16 bf16;
typedef __bf16 bf16x8 __attribute__((ext_vector_type(8)));
typedef __bf16 bf16x4 __attribute__((ext_vector_type(4)));
typedef float floatx4 __attribute__((ext_vector_type(4)));

#define T_TOK 4096
#define Dm    1024
#define Hm    512
#define Em    32
#define HsDim 1024   // shared inter dim
#define Hs2   2048   // 2*HsDim (concat W1|W3 columns)
#define Pp    16384  // T*K pairs
#define CAP   2048   // per-expert capacity

// ---------------------------------------------------------------- gate ------
// One wave per 4 tokens. fp32 logits (match reference routing), softmax,
// stable top-4 (ties -> lower index, same as lax.top_k).
__global__ __launch_bounds__(64) void gate_kernel(
    const float* __restrict__ xf, const float* __restrict__ Wg,
    int* __restrict__ topk_e, float* __restrict__ topk_w, int* __restrict__ cnt)
{
    __shared__ float xs[4][Dm];
    int lane = threadIdx.x;
    int t0 = blockIdx.x * 4;
    const float4* src = (const float4*)(xf + (size_t)t0 * Dm);
    float4* dst = (float4*)&xs[0][0];
#pragma unroll
    for (int i = 0; i < 16; ++i) dst[lane + i * 64] = src[lane + i * 64];
    __syncthreads();

    int e = lane & 31;
    float a0 = 0.f, a1 = 0.f, a2 = 0.f, a3 = 0.f;
    for (int d = 0; d < Dm; ++d) {
        float w = Wg[d * Em + e];
        a0 = fmaf(xs[0][d], w, a0);
        a1 = fmaf(xs[1][d], w, a1);
        a2 = fmaf(xs[2][d], w, a2);
        a3 = fmaf(xs[3][d], w, a3);
    }
    float la[4] = {a0, a1, a2, a3};
#pragma unroll
    for (int tt = 0; tt < 4; ++tt) {
        float s = la[tt];
        float M = s;
        for (int m = 16; m >= 1; m >>= 1) M = fmaxf(M, __shfl_xor(M, m));
        float sum = __expf(s - M);
        for (int m = 16; m >= 1; m >>= 1) sum += __shfl_xor(sum, m);
        float act = s;
        for (int k = 0; k < 4; ++k) {
            float v = act; int idx = e;
            for (int m = 16; m >= 1; m >>= 1) {
                float ov = __shfl_xor(v, m);
                int   oi = __shfl_xor(idx, m);
                if (ov > v || (ov == v && oi < idx)) { v = ov; idx = oi; }
            }
            if (lane == 0) {
                int t = t0 + tt;
                topk_e[t * 4 + k] = idx;
                topk_w[t * 4 + k] = __expf(v - M) / sum;
                atomicAdd(&cnt[idx], 1);
            }
            if (e == idx) act = -3.0e38f;
        }
    }
}

__global__ void offsets_kernel(const int* __restrict__ cnt, int* __restrict__ cntc,
                               int* __restrict__ offs)
{
    if (threadIdx.x == 0) {
        int run = 0;
        for (int e = 0; e < Em; ++e) {
            int c = cnt[e]; if (c > CAP) c = CAP;
            cntc[e] = c; offs[e] = run; run += c;
        }
        offs[Em] = run;
    }
}

__global__ void scatter_kernel(const int* __restrict__ topk_e, const float* __restrict__ topk_w,
                               const int* __restrict__ cntc, const int* __restrict__ offs,
                               int* __restrict__ cnt2, int* __restrict__ tok_c,
                               float* __restrict__ wt_c)
{
    int p = blockIdx.x * 256 + threadIdx.x;
    if (p >= Pp) return;
    int e = topk_e[p];
    int slot = atomicAdd(&cnt2[e], 1);
    if (slot < cntc[e]) {
        int rc = offs[e] + slot;
        tok_c[rc] = p >> 2;
        wt_c[rc] = topk_w[p];
    }
}

// ---------------------------------------------------------------- casts -----
__global__ void cast_x_kernel(const float* __restrict__ src, bf16* __restrict__ dst, int n4)
{
    int i = blockIdx.x * 256 + threadIdx.x;
    if (i >= n4) return;
    float4 v = ((const float4*)src)[i];
    bf16x4 o = {(bf16)v.x, (bf16)v.y, (bf16)v.z, (bf16)v.w};
    ((bf16x4*)dst)[i] = o;
}

// src: batches of (R x Cc) fp32 row-major -> dst: (Cc x R) bf16 row-major.
__global__ void transpose_cast(const float* __restrict__ src, bf16* __restrict__ dst,
                               int R, int Cc, long sstride, long dstride)
{
    __shared__ float t[32][33];
    int b = blockIdx.z;
    src += (long)b * sstride;
    dst += (long)b * dstride;
    int r0 = blockIdx.y * 32, c0 = blockIdx.x * 32;
    int tx = threadIdx.x, ty = threadIdx.y;
#pragma unroll
    for (int i = 0; i < 4; ++i)
        t[ty + i * 8][tx] = src[(long)(r0 + ty + i * 8) * Cc + (c0 + tx)];
    __syncthreads();
#pragma unroll
    for (int i = 0; i < 4; ++i)
        dst[(long)(c0 + ty + i * 8) * R + (r0 + tx)] = (bf16)t[tx][ty + i * 8];
}

// ---------------------------------------------------------------- act -------
// hh[r][h] = silu(g1[r][h]) * g1[r][hoff+h]; hh leading dim = hoff.
__global__ void act_kernel(const bf16* __restrict__ g1, bf16* __restrict__ hh,
                           const int* __restrict__ total_ptr, int total_const,
                           int ldg, int hoff, int shift)
{
    int total = total_const;
    if (total_ptr) total = *total_ptr;
    int gid = blockIdx.x * 256 + threadIdx.x;
    int r = gid >> shift;
    if (r >= total) return;
    int h = (gid & ((1 << shift) - 1)) * 4;
    const bf16* row = g1 + (size_t)r * ldg;
    bf16x4 a4 = *(const bf16x4*)(row + h);
    bf16x4 b4 = *(const bf16x4*)(row + hoff + h);
    bf16x4 o;
#pragma unroll
    for (int i = 0; i < 4; ++i) {
        float a = (float)a4[i], b = (float)b4[i];
        float sg = 1.0f / (1.0f + __expf(-a));
        o[i] = (bf16)(a * sg * b);
    }
    *(bf16x4*)(hh + (size_t)r * hoff + h) = o;
}

// ---------------------------------------------------------------- GEMM ------
// C[m,n] = sum_k A[m,k] * BT[n,k].  128x128 tile, BK=64, 4 waves (each 64x64),
// mfma_f32_16x16x32_bf16.  global_load_lds width-16; LDS chunk columns XOR-
// swizzled by (row&7) so MFMA ds_read_b128 (stride 128B over 16 lanes) is
// conflict-free — padding is impossible under global_load_lds.
// MODE 0: store bf16 raw at compact rows. 1: atomicAdd(out[tok[r]]) * wt[r].
// 2: plain fp32 store.
__device__ __forceinline__ void gload_lds16(const bf16* g, bf16* l)
{
    __builtin_amdgcn_global_load_lds((const __attribute__((address_space(1))) void*)g,
                                     (__attribute__((address_space(3))) void*)l, 16, 0, 0);
}

template <int MODE, bool EXPERT, bool GATHER>
__global__ void __launch_bounds__(256, 2) gemm_bt(
    const bf16* __restrict__ A, const bf16* __restrict__ BT,
    int K, int N, int lda,
    const int* __restrict__ cntc, const int* __restrict__ offs,
    const int* __restrict__ tok, const float* __restrict__ wt,
    long strideBT,
    bf16* __restrict__ outB, float* __restrict__ outF, int ldo, int mtotal)
{
    __shared__ __align__(16) bf16 As[128 * 64];
    __shared__ __align__(16) bf16 Bs[128 * 64];

    int mt, mcount, rowbase;
    if (EXPERT) {
        int e = blockIdx.y >> 4;          // CAP/128 = 16 m-tiles per expert
        mt = blockIdx.y & 15;
        mcount = cntc[e];
        if (mt * 128 >= mcount) return;
        rowbase = offs[e];
        BT += (long)e * strideBT;
    } else {
        mt = blockIdx.y; mcount = mtotal; rowbase = 0;
    }
    int nt = blockIdx.x;

    int tid = threadIdx.x;
    int wave = tid >> 6, lane = tid & 63;
    int wm = wave >> 1, wn = wave & 1;
    int q = lane >> 4, lm = lane & 15;

    floatx4 acc[4][4] = {};

    // Per-thread staging pointers: 4 chunks of A + 4 of B per thread.
    const bf16* arow[4];
    const bf16* brow[4];
#pragma unroll
    for (int it = 0; it < 4; ++it) {
        int c = wave * 256 + it * 64 + lane;
        int row = c >> 3;
        int kc = (c & 7) ^ (row & 7);      // XOR swizzle on 16B chunks
        int rl = mt * 128 + row;
        int rr = rl < mcount ? rl : mcount - 1;
        long aoff;
        if (GATHER) aoff = (long)tok[rowbase + rr] * lda;
        else        aoff = (long)(rowbase + rr) * lda;
        arow[it] = A + aoff + kc * 8;
        brow[it] = BT + (long)(nt * 128 + row) * K + kc * 8;
    }

    for (int kt = 0; kt < K; kt += 64) {
#pragma unroll
        for (int it = 0; it < 4; ++it)
            gload_lds16(arow[it] + kt, As + (wave * 256 + it * 64) * 8);
#pragma unroll
        for (int it = 0; it < 4; ++it)
            gload_lds16(brow[it] + kt, Bs + (wave * 256 + it * 64) * 8);
        __syncthreads();
#pragma unroll
        for (int kk = 0; kk < 2; ++kk) {
            bf16x8 af[4], bfv[4];
            int j = kk * 4 + q;
#pragma unroll
            for (int i = 0; i < 4; ++i) {
                int row = wm * 64 + i * 16 + lm;
                af[i] = *(const bf16x8*)(As + row * 64 + ((j ^ (row & 7)) * 8));
            }
#pragma unroll
            for (int j2 = 0; j2 < 4; ++j2) {
                int row = wn * 64 + j2 * 16 + lm;
                bfv[j2] = *(const bf16x8*)(Bs + row * 64 + ((j ^ (row & 7)) * 8));
            }
#pragma unroll
            for (int i = 0; i < 4; ++i)
#pragma unroll
                for (int j2 = 0; j2 < 4; ++j2)
                    acc[i][j2] = __builtin_amdgcn_mfma_f32_16x16x32_bf16(
                        af[i], bfv[j2], acc[i][j2], 0, 0, 0);
        }
        __syncthreads();
    }

    int colbase = nt * 128 + wn * 64;
#pragma unroll
    for (int i = 0; i < 4; ++i) {
        int rloc = wm * 64 + i * 16 + q * 4;
#pragma unroll
        for (int r = 0; r < 4; ++r) {
            int rl = mt * 128 + rloc + r;
            if (rl >= mcount) continue;
            int t = 0; float w = 0.f;
            if (MODE == 1) { t = tok[rowbase + rl]; w = wt[rowbase + rl]; }
#pragma unroll
            for (int j2 = 0; j2 < 4; ++j2) {
                int col = colbase + j2 * 16 + lm;
                float v = acc[i][j2][r];
                if (MODE == 0)      outB[(long)(rowbase + rl) * ldo + col] = (bf16)v;
                else if (MODE == 1) atomicAdd(outF + (long)t * ldo + col, v * w);
                else                outF[(long)rl * ldo + col] = v;
            }
        }
    }
}

// ---------------------------------------------------------------- launch ----
extern "C" void kernel_launch(void* const* d_in, const int* in_sizes, int n_in,
                              void* d_out, int out_size, void* d_ws, size_t ws_size,
                              hipStream_t stream)
{
    const float* x   = (const float*)d_in[0];
    const float* Wg  = (const float*)d_in[1];
    const float* W1  = (const float*)d_in[2];
    const float* W2  = (const float*)d_in[3];
    const float* W3  = (const float*)d_in[4];
    const float* Ws1 = (const float*)d_in[5];
    const float* Ws2 = (const float*)d_in[6];
    const float* Ws3 = (const float*)d_in[7];
    float* out = (float*)d_out;

    char* p = (char*)d_ws;
    auto alloc = [&](size_t bytes) {
        char* r = p; p += (bytes + 255) & ~(size_t)255; return r;
    };
    bf16*  xb    = (bf16*)alloc((size_t)T_TOK * Dm * 2);
    bf16*  W13T  = (bf16*)alloc((size_t)Em * 2 * Hm * Dm * 2);
    bf16*  W2T   = (bf16*)alloc((size_t)Em * Dm * Hm * 2);
    bf16*  Ws13T = (bf16*)alloc((size_t)Hs2 * Dm * 2);
    bf16*  Ws2T  = (bf16*)alloc((size_t)Dm * HsDim * 2);
    bf16*  G1    = (bf16*)alloc((size_t)Pp * 1024 * 2);  // shared path aliases (4096x2048)
    bf16*  Hh    = (bf16*)alloc((size_t)Pp * Hm * 2);    // shared path aliases (4096x1024)
    int*   topkE = (int*)alloc(Pp * 4);
    float* topkW = (float*)alloc(Pp * 4);
    int*   tokC  = (int*)alloc(Pp * 4);
    float* wtC   = (float*)alloc(Pp * 4);
    int*   cnt   = (int*)alloc(128);
    int*   cnt2  = (int*)alloc(128);
    int*   cntc  = (int*)alloc(128);
    int*   offs  = (int*)alloc(256);

    size_t need = (size_t)(p - (char*)d_ws);
    if (ws_size < need) {
        fprintf(stderr, "kernel_launch: ws too small (%zu < %zu)\n", ws_size, need);
        return;
    }

    hipMemsetAsync(cnt, 0, 1024, stream);  // cnt, cnt2, cntc, offs

    // Routing (fp32, matches reference top-k exactly)
    gate_kernel<<<T_TOK / 4, 64, 0, stream>>>(x, Wg, topkE, topkW, cnt);
    offsets_kernel<<<1, 64, 0, stream>>>(cnt, cntc, offs);
    scatter_kernel<<<Pp / 256, 256, 0, stream>>>(topkE, topkW, cntc, offs, cnt2, tokC, wtC);

    // bf16 casts / B^T layouts
    cast_x_kernel<<<(T_TOK * Dm / 4) / 256, 256, 0, stream>>>(x, xb, T_TOK * Dm / 4);
    transpose_cast<<<dim3(Hm / 32, Dm / 32, Em), dim3(32, 8), 0, stream>>>(
        W1, W13T, Dm, Hm, (long)Dm * Hm, (long)2 * Hm * Dm);
    transpose_cast<<<dim3(Hm / 32, Dm / 32, Em), dim3(32, 8), 0, stream>>>(
        W3, W13T + (size_t)Hm * Dm, Dm, Hm, (long)Dm * Hm, (long)2 * Hm * Dm);
    transpose_cast<<<dim3(Dm / 32, Hm / 32, Em), dim3(32, 8), 0, stream>>>(
        W2, W2T, Hm, Dm, (long)Hm * Dm, (long)Hm * Dm);
    transpose_cast<<<dim3(HsDim / 32, Dm / 32, 1), dim3(32, 8), 0, stream>>>(
        Ws1, Ws13T, Dm, HsDim, 0, 0);
    transpose_cast<<<dim3(HsDim / 32, Dm / 32, 1), dim3(32, 8), 0, stream>>>(
        Ws3, Ws13T + (size_t)HsDim * Dm, Dm, HsDim, 0, 0);
    transpose_cast<<<dim3(Dm / 32, HsDim / 32, 1), dim3(32, 8), 0, stream>>>(
        Ws2, Ws2T, HsDim, Dm, 0, 0);

    // Shared experts first: plain stores write z to every d_out element.
    gemm_bt<0, false, false><<<dim3(Hs2 / 128, T_TOK / 128), 256, 0, stream>>>(
        xb, Ws13T, Dm, Hs2, Dm, nullptr, nullptr, nullptr, nullptr, 0,
        G1, nullptr, Hs2, T_TOK);
    act_kernel<<<T_TOK * (HsDim / 4) / 256, 256, 0, stream>>>(
        G1, Hh, nullptr, T_TOK, Hs2, HsDim, 8);
    gemm_bt<2, false, false><<<dim3(Dm / 128, T_TOK / 128), 256, 0, stream>>>(
        Hh, Ws2T, HsDim, Dm, HsDim, nullptr, nullptr, nullptr, nullptr, 0,
        nullptr, out, Dm, T_TOK);

    // Routed experts: gather-GEMM1 -> silu*mul -> GEMM2 with weighted scatter-add.
    gemm_bt<0, true, true><<<dim3(1024 / 128, Em * (CAP / 128)), 256, 0, stream>>>(
        xb, W13T, Dm, 1024, Dm, cntc, offs, tokC, nullptr, (long)2 * Hm * Dm,
        G1, nullptr, 1024, 0);
    act_kernel<<<Pp * (Hm / 4) / 256, 256, 0, stream>>>(
        G1, Hh, offs + Em, 0, 1024, Hm, 7);
    gemm_bt<1, true, false><<<dim3(Dm / 128, Em * (CAP / 128)), 256, 0, stream>>>(
        Hh, W2T, Hm, Dm, Hm, cntc, offs, tokC, wtC, (long)Hm * Dm,
        nullptr, out, Dm, 0);
}

// Round 2
// 507.647 us; speedup vs baseline: 1.2487x; 1.2487x over previous
//
#include <hip/hip_runtime.h>
#include <cstdio>

typedef __bf16 bf16;
typedef __bf16 bf16x8 __attribute__((ext_vector_type(8)));
typedef __bf16 bf16x4 __attribute__((ext_vector_type(4)));
typedef float floatx4 __attribute__((ext_vector_type(4)));

#define T_TOK 4096
#define Dm    1024
#define Hm    512
#define Em    32
#define HsDim 1024   // shared inter dim
#define Hs2   2048   // 2*HsDim (concat W1|W3 columns)
#define Pp    16384  // T*K pairs
#define CAP   2048   // per-expert capacity

// ---------------------------------------------------------------- gate ------
// Stage 1: logits[t][e] = x[t][:] . Wg[:][e], fp32 (must match reference
// routing exactly -> no bf16 here). 8 tokens/block, thread=(token,expert).
// x rows + transposed-free Wg chunks staged in LDS; all LDS reads are
// broadcast or bank-perfect.
__global__ __launch_bounds__(256) void gate_logits(
    const float* __restrict__ xf, const float* __restrict__ Wg,
    float* __restrict__ logits)
{
    __shared__ float xs[8][Dm];        // 32 KB
    __shared__ float wsC[128 * Em];    // 16 KB, natural [d][e] layout
    int tid = threadIdx.x;
    int t0 = blockIdx.x * 8;

    const float4* src = (const float4*)(xf + (size_t)t0 * Dm);
    float4* dst = (float4*)&xs[0][0];
#pragma unroll
    for (int i = 0; i < 8; ++i) dst[tid + i * 256] = src[tid + i * 256];

    int tg = tid >> 5, e = tid & 31;
    float acc = 0.f;
    for (int d0 = 0; d0 < Dm; d0 += 128) {
        __syncthreads();               // covers xs on iter 0, wsC reuse after
        const float4* wg4 = (const float4*)(Wg + (size_t)d0 * Em);
        float4* ws4 = (float4*)wsC;
#pragma unroll
        for (int i = 0; i < 4; ++i) ws4[tid + i * 256] = wg4[tid + i * 256];
        __syncthreads();
#pragma unroll
        for (int d = 0; d < 128; d += 4) {
            float4 xv = *(const float4*)&xs[tg][d0 + d];
            acc = fmaf(xv.x, wsC[(d + 0) * Em + e], acc);
            acc = fmaf(xv.y, wsC[(d + 1) * Em + e], acc);
            acc = fmaf(xv.z, wsC[(d + 2) * Em + e], acc);
            acc = fmaf(xv.w, wsC[(d + 3) * Em + e], acc);
        }
    }
    logits[(size_t)(t0 + tg) * Em + e] = acc;
}

// Stage 2: per-token softmax + stable top-4 (ties -> lower index, same as
// lax.top_k). One thread per token; LDS histogram -> 1 atomic/expert/block.
__global__ __launch_bounds__(256) void gate_topk(
    const float* __restrict__ logits, int* __restrict__ topk_e,
    float* __restrict__ topk_w, int* __restrict__ cnt)
{
    __shared__ int hist[Em];
    int tid = threadIdx.x;
    if (tid < Em) hist[tid] = 0;
    __syncthreads();

    int t = blockIdx.x * 256 + tid;
    float l[Em];
    float M = -3.0e38f;
#pragma unroll
    for (int i = 0; i < 8; ++i) {
        float4 v = *(const float4*)(logits + (size_t)t * Em + i * 4);
        l[i * 4 + 0] = v.x; l[i * 4 + 1] = v.y;
        l[i * 4 + 2] = v.z; l[i * 4 + 3] = v.w;
        M = fmaxf(M, fmaxf(fmaxf(v.x, v.y), fmaxf(v.z, v.w)));
    }
    float sum = 0.f;
#pragma unroll
    for (int i = 0; i < Em; ++i) sum += __expf(l[i] - M);
    float inv = 1.0f / sum;
#pragma unroll
    for (int k = 0; k < 4; ++k) {
        float best = -3.0e38f; int bi = 0;
#pragma unroll
        for (int i = 0; i < Em; ++i)
            if (l[i] > best) { best = l[i]; bi = i; }
        topk_e[t * 4 + k] = bi;
        topk_w[t * 4 + k] = __expf(best - M) * inv;
        atomicAdd(&hist[bi], 1);
#pragma unroll
        for (int i = 0; i < Em; ++i)
            if (i == bi) l[i] = -3.0e38f;
    }
    __syncthreads();
    if (tid < Em) { int h = hist[tid]; if (h) atomicAdd(&cnt[tid], h); }
}

__global__ void offsets_kernel(const int* __restrict__ cnt, int* __restrict__ cntc,
                               int* __restrict__ offs)
{
    if (threadIdx.x == 0) {
        int run = 0;
        for (int e = 0; e < Em; ++e) {
            int c = cnt[e]; if (c > CAP) c = CAP;
            cntc[e] = c; offs[e] = run; run += c;
        }
        offs[Em] = run;
    }
}

__global__ void scatter_kernel(const int* __restrict__ topk_e, const float* __restrict__ topk_w,
                               const int* __restrict__ cntc, const int* __restrict__ offs,
                               int* __restrict__ cnt2, int* __restrict__ tok_c,
                               float* __restrict__ wt_c)
{
    int p = blockIdx.x * 256 + threadIdx.x;
    if (p >= Pp) return;
    int e = topk_e[p];
    int slot = atomicAdd(&cnt2[e], 1);
    if (slot < cntc[e]) {
        int rc = offs[e] + slot;
        tok_c[rc] = p >> 2;
        wt_c[rc] = topk_w[p];
    }
}

// ---------------------------------------------------------------- casts -----
__global__ void cast_x_kernel(const float* __restrict__ src, bf16* __restrict__ dst, int n4)
{
    int i = blockIdx.x * 256 + threadIdx.x;
    if (i >= n4) return;
    float4 v = ((const float4*)src)[i];
    bf16x4 o = {(bf16)v.x, (bf16)v.y, (bf16)v.z, (bf16)v.w};
    ((bf16x4*)dst)[i] = o;
}

// src: batches of (R x Cc) fp32 row-major -> dst: (Cc x R) bf16 row-major.
__global__ void transpose_cast(const float* __restrict__ src, bf16* __restrict__ dst,
                               int R, int Cc, long sstride, long dstride)
{
    __shared__ float t[32][33];
    int b = blockIdx.z;
    src += (long)b * sstride;
    dst += (long)b * dstride;
    int r0 = blockIdx.y * 32, c0 = blockIdx.x * 32;
    int tx = threadIdx.x, ty = threadIdx.y;
#pragma unroll
    for (int i = 0; i < 4; ++i)
        t[ty + i * 8][tx] = src[(long)(r0 + ty + i * 8) * Cc + (c0 + tx)];
    __syncthreads();
#pragma unroll
    for (int i = 0; i < 4; ++i)
        dst[(long)(c0 + ty + i * 8) * R + (r0 + tx)] = (bf16)t[tx][ty + i * 8];
}

// ---------------------------------------------------------------- act -------
// hh[r][h] = silu(g1[r][h]) * g1[r][hoff+h]; hh leading dim = hoff.
__global__ void act_kernel(const bf16* __restrict__ g1, bf16* __restrict__ hh,
                           const int* __restrict__ total_ptr, int total_const,
                           int ldg, int hoff, int shift)
{
    int total = total_const;
    if (total_ptr) total = *total_ptr;
    int gid = blockIdx.x * 256 + threadIdx.x;
    int r = gid >> shift;
    if (r >= total) return;
    int h = (gid & ((1 << shift) - 1)) * 4;
    const bf16* row = g1 + (size_t)r * ldg;
    bf16x4 a4 = *(const bf16x4*)(row + h);
    bf16x4 b4 = *(const bf16x4*)(row + hoff + h);
    bf16x4 o;
#pragma unroll
    for (int i = 0; i < 4; ++i) {
        float a = (float)a4[i], b = (float)b4[i];
        float sg = 1.0f / (1.0f + __expf(-a));
        o[i] = (bf16)(a * sg * b);
    }
    *(bf16x4*)(hh + (size_t)r * hoff + h) = o;
}

// ---------------------------------------------------------------- GEMM ------
// C[m,n] = sum_k A[m,k] * BT[n,k].  128x128 tile, BK=64, 4 waves (each 64x64),
// mfma_f32_16x16x32_bf16.  global_load_lds width-16; LDS chunk columns XOR-
// swizzled by (row&7) so MFMA ds_read_b128 (stride 128B over 16 lanes) is
// conflict-free — padding is impossible under global_load_lds.
// MODE 0: store bf16 raw at compact rows. 1: atomicAdd(out[tok[r]]) * wt[r].
// 2: plain fp32 store.
__device__ __forceinline__ void gload_lds16(const bf16* g, bf16* l)
{
    __builtin_amdgcn_global_load_lds((const __attribute__((address_space(1))) void*)g,
                                     (__attribute__((address_space(3))) void*)l, 16, 0, 0);
}

template <int MODE, bool EXPERT, bool GATHER>
__global__ void __launch_bounds__(256, 2) gemm_bt(
    const bf16* __restrict__ A, const bf16* __restrict__ BT,
    int K, int N, int lda,
    const int* __restrict__ cntc, const int* __restrict__ offs,
    const int* __restrict__ tok, const float* __restrict__ wt,
    long strideBT,
    bf16* __restrict__ outB, float* __restrict__ outF, int ldo, int mtotal)
{
    __shared__ __align__(16) bf16 As[128 * 64];
    __shared__ __align__(16) bf16 Bs[128 * 64];

    int mt, mcount, rowbase;
    if (EXPERT) {
        int e = blockIdx.y >> 4;          // CAP/128 = 16 m-tiles per expert
        mt = blockIdx.y & 15;
        mcount = cntc[e];
        if (mt * 128 >= mcount) return;
        rowbase = offs[e];
        BT += (long)e * strideBT;
    } else {
        mt = blockIdx.y; mcount = mtotal; rowbase = 0;
    }
    int nt = blockIdx.x;

    int tid = threadIdx.x;
    int wave = tid >> 6, lane = tid & 63;
    int wm = wave >> 1, wn = wave & 1;
    int q = lane >> 4, lm = lane & 15;

    floatx4 acc[4][4] = {};

    // Per-thread staging pointers: 4 chunks of A + 4 of B per thread.
    const bf16* arow[4];
    const bf16* brow[4];
#pragma unroll
    for (int it = 0; it < 4; ++it) {
        int c = wave * 256 + it * 64 + lane;
        int row = c >> 3;
        int kc = (c & 7) ^ (row & 7);      // XOR swizzle on 16B chunks
        int rl = mt * 128 + row;
        int rr = rl < mcount ? rl : mcount - 1;
        long aoff;
        if (GATHER) aoff = (long)tok[rowbase + rr] * lda;
        else        aoff = (long)(rowbase + rr) * lda;
        arow[it] = A + aoff + kc * 8;
        brow[it] = BT + (long)(nt * 128 + row) * K + kc * 8;
    }

    for (int kt = 0; kt < K; kt += 64) {
#pragma unroll
        for (int it = 0; it < 4; ++it)
            gload_lds16(arow[it] + kt, As + (wave * 256 + it * 64) * 8);
#pragma unroll
        for (int it = 0; it < 4; ++it)
            gload_lds16(brow[it] + kt, Bs + (wave * 256 + it * 64) * 8);
        __syncthreads();
#pragma unroll
        for (int kk = 0; kk < 2; ++kk) {
            bf16x8 af[4], bfv[4];
            int j = kk * 4 + q;
#pragma unroll
            for (int i = 0; i < 4; ++i) {
                int row = wm * 64 + i * 16 + lm;
                af[i] = *(const bf16x8*)(As + row * 64 + ((j ^ (row & 7)) * 8));
            }
#pragma unroll
            for (int j2 = 0; j2 < 4; ++j2) {
                int row = wn * 64 + j2 * 16 + lm;
                bfv[j2] = *(const bf16x8*)(Bs + row * 64 + ((j ^ (row & 7)) * 8));
            }
#pragma unroll
            for (int i = 0; i < 4; ++i)
#pragma unroll
                for (int j2 = 0; j2 < 4; ++j2)
                    acc[i][j2] = __builtin_amdgcn_mfma_f32_16x16x32_bf16(
                        af[i], bfv[j2], acc[i][j2], 0, 0, 0);
        }
        __syncthreads();
    }

    int colbase = nt * 128 + wn * 64;
#pragma unroll
    for (int i = 0; i < 4; ++i) {
        int rloc = wm * 64 + i * 16 + q * 4;
#pragma unroll
        for (int r = 0; r < 4; ++r) {
            int rl = mt * 128 + rloc + r;
            if (rl >= mcount) continue;
            int t = 0; float w = 0.f;
            if (MODE == 1) { t = tok[rowbase + rl]; w = wt[rowbase + rl]; }
#pragma unroll
            for (int j2 = 0; j2 < 4; ++j2) {
                int col = colbase + j2 * 16 + lm;
                float v = acc[i][j2][r];
                if (MODE == 0)      outB[(long)(rowbase + rl) * ldo + col] = (bf16)v;
                else if (MODE == 1) atomicAdd(outF + (long)t * ldo + col, v * w);
                else                outF[(long)rl * ldo + col] = v;
            }
        }
    }
}

// ---------------------------------------------------------------- launch ----
extern "C" void kernel_launch(void* const* d_in, const int* in_sizes, int n_in,
                              void* d_out, int out_size, void* d_ws, size_t ws_size,
                              hipStream_t stream)
{
    const float* x   = (const float*)d_in[0];
    const float* Wg  = (const float*)d_in[1];
    const float* W1  = (const float*)d_in[2];
    const float* W2  = (const float*)d_in[3];
    const float* W3  = (const float*)d_in[4];
    const float* Ws1 = (const float*)d_in[5];
    const float* Ws2 = (const float*)d_in[6];
    const float* Ws3 = (const float*)d_in[7];
    float* out = (float*)d_out;

    char* p = (char*)d_ws;
    auto alloc = [&](size_t bytes) {
        char* r = p; p += (bytes + 255) & ~(size_t)255; return r;
    };
    bf16*  xb    = (bf16*)alloc((size_t)T_TOK * Dm * 2);
    bf16*  W13T  = (bf16*)alloc((size_t)Em * 2 * Hm * Dm * 2);
    bf16*  W2T   = (bf16*)alloc((size_t)Em * Dm * Hm * 2);
    bf16*  Ws13T = (bf16*)alloc((size_t)Hs2 * Dm * 2);
    bf16*  Ws2T  = (bf16*)alloc((size_t)Dm * HsDim * 2);
    bf16*  G1    = (bf16*)alloc((size_t)Pp * 1024 * 2);  // shared path aliases (4096x2048)
    bf16*  Hh    = (bf16*)alloc((size_t)Pp * Hm * 2);    // shared path aliases (4096x1024)
    float* logits= (float*)alloc((size_t)T_TOK * Em * 4);
    int*   topkE = (int*)alloc(Pp * 4);
    float* topkW = (float*)alloc(Pp * 4);
    int*   tokC  = (int*)alloc(Pp * 4);
    float* wtC   = (float*)alloc(Pp * 4);
    int*   cnt   = (int*)alloc(128);
    int*   cnt2  = (int*)alloc(128);
    int*   cntc  = (int*)alloc(128);
    int*   offs  = (int*)alloc(256);

    size_t need = (size_t)(p - (char*)d_ws);
    if (ws_size < need) {
        fprintf(stderr, "kernel_launch: ws too small (%zu < %zu)\n", ws_size, need);
        return;
    }

    hipMemsetAsync(cnt, 0, 1024, stream);  // cnt, cnt2, cntc, offs

    // Routing (fp32, matches reference top-k exactly)
    gate_logits<<<T_TOK / 8, 256, 0, stream>>>(x, Wg, logits);
    gate_topk<<<T_TOK / 256, 256, 0, stream>>>(logits, topkE, topkW, cnt);
    offsets_kernel<<<1, 64, 0, stream>>>(cnt, cntc, offs);
    scatter_kernel<<<Pp / 256, 256, 0, stream>>>(topkE, topkW, cntc, offs, cnt2, tokC, wtC);

    // bf16 casts / B^T layouts
    cast_x_kernel<<<(T_TOK * Dm / 4) / 256, 256, 0, stream>>>(x, xb, T_TOK * Dm / 4);
    transpose_cast<<<dim3(Hm / 32, Dm / 32, Em), dim3(32, 8), 0, stream>>>(
        W1, W13T, Dm, Hm, (long)Dm * Hm, (long)2 * Hm * Dm);
    transpose_cast<<<dim3(Hm / 32, Dm / 32, Em), dim3(32, 8), 0, stream>>>(
        W3, W13T + (size_t)Hm * Dm, Dm, Hm, (long)Dm * Hm, (long)2 * Hm * Dm);
    transpose_cast<<<dim3(Dm / 32, Hm / 32, Em), dim3(32, 8), 0, stream>>>(
        W2, W2T, Hm, Dm, (long)Hm * Dm, (long)Hm * Dm);
    transpose_cast<<<dim3(HsDim / 32, Dm / 32, 1), dim3(32, 8), 0, stream>>>(
        Ws1, Ws13T, Dm, HsDim, 0, 0);
    transpose_cast<<<dim3(HsDim / 32, Dm / 32, 1), dim3(32, 8), 0, stream>>>(
        Ws3, Ws13T + (size_t)HsDim * Dm, Dm, HsDim, 0, 0);
    transpose_cast<<<dim3(Dm / 32, HsDim / 32, 1), dim3(32, 8), 0, stream>>>(
        Ws2, Ws2T, HsDim, Dm, 0, 0);

    // Shared experts first: plain stores write z to every d_out element.
    gemm_bt<0, false, false><<<dim3(Hs2 / 128, T_TOK / 128), 256, 0, stream>>>(
        xb, Ws13T, Dm, Hs2, Dm, nullptr, nullptr, nullptr, nullptr, 0,
        G1, nullptr, Hs2, T_TOK);
    act_kernel<<<T_TOK * (HsDim / 4) / 256, 256, 0, stream>>>(
        G1, Hh, nullptr, T_TOK, Hs2, HsDim, 8);
    gemm_bt<2, false, false><<<dim3(Dm / 128, T_TOK / 128), 256, 0, stream>>>(
        Hh, Ws2T, HsDim, Dm, HsDim, nullptr, nullptr, nullptr, nullptr, 0,
        nullptr, out, Dm, T_TOK);

    // Routed experts: gather-GEMM1 -> silu*mul -> GEMM2 with weighted scatter-add.
    gemm_bt<0, true, true><<<dim3(1024 / 128, Em * (CAP / 128)), 256, 0, stream>>>(
        xb, W13T, Dm, 1024, Dm, cntc, offs, tokC, nullptr, (long)2 * Hm * Dm,
        G1, nullptr, 1024, 0);
    act_kernel<<<Pp * (Hm / 4) / 256, 256, 0, stream>>>(
        G1, Hh, offs + Em, 0, 1024, Hm, 7);
    gemm_bt<1, true, false><<<dim3(Dm / 128, Em * (CAP / 128)), 256, 0, stream>>>(
        Hh, W2T, Hm, Dm, Hm, cntc, offs, tokC, wtC, (long)Hm * Dm,
        nullptr, out, Dm, 0);
}

// Round 3
// 482.061 us; speedup vs baseline: 1.3150x; 1.0531x over previous
//
#include <hip/hip_runtime.h>
#include <cstdio>

typedef __bf16 bf16;
typedef __bf16 bf16x8 __attribute__((ext_vector_type(8)));
typedef __bf16 bf16x4 __attribute__((ext_vector_type(4)));
typedef float floatx4 __attribute__((ext_vector_type(4)));

#define T_TOK 4096
#define Dm    1024
#define Hm    512
#define Em    32
#define HsDim 1024   // shared inter dim
#define Hs2   2048   // 2*HsDim (concat W1|W3 rows in BT layout)
#define Pp    16384  // T*K pairs
#define CAP   2048   // per-expert capacity

// ---------------------------------------------------------------- gate ------
// Stage 1: logits[t][e] = x[t][:] . Wg[:][e], fp32 (must match reference
// routing exactly -> no bf16 here). 8 tokens/block, thread=(token,expert).
__global__ __launch_bounds__(256) void gate_logits(
    const float* __restrict__ xf, const float* __restrict__ Wg,
    float* __restrict__ logits)
{
    __shared__ float xs[8][Dm];        // 32 KB
    __shared__ float wsC[128 * Em];    // 16 KB, natural [d][e] layout
    int tid = threadIdx.x;
    int t0 = blockIdx.x * 8;

    const float4* src = (const float4*)(xf + (size_t)t0 * Dm);
    float4* dst = (float4*)&xs[0][0];
#pragma unroll
    for (int i = 0; i < 8; ++i) dst[tid + i * 256] = src[tid + i * 256];

    int tg = tid >> 5, e = tid & 31;
    float acc = 0.f;
    for (int d0 = 0; d0 < Dm; d0 += 128) {
        __syncthreads();               // covers xs on iter 0, wsC reuse after
        const float4* wg4 = (const float4*)(Wg + (size_t)d0 * Em);
        float4* ws4 = (float4*)wsC;
#pragma unroll
        for (int i = 0; i < 4; ++i) ws4[tid + i * 256] = wg4[tid + i * 256];
        __syncthreads();
#pragma unroll
        for (int d = 0; d < 128; d += 4) {
            float4 xv = *(const float4*)&xs[tg][d0 + d];
            acc = fmaf(xv.x, wsC[(d + 0) * Em + e], acc);
            acc = fmaf(xv.y, wsC[(d + 1) * Em + e], acc);
            acc = fmaf(xv.z, wsC[(d + 2) * Em + e], acc);
            acc = fmaf(xv.w, wsC[(d + 3) * Em + e], acc);
        }
    }
    logits[(size_t)(t0 + tg) * Em + e] = acc;
}

// Stage 2: per-token softmax + stable top-4 (ties -> lower index, same as
// lax.top_k). One thread per token; LDS histogram -> 1 atomic/expert/block.
__global__ __launch_bounds__(256) void gate_topk(
    const float* __restrict__ logits, int* __restrict__ topk_e,
    float* __restrict__ topk_w, int* __restrict__ cnt)
{
    __shared__ int hist[Em];
    int tid = threadIdx.x;
    if (tid < Em) hist[tid] = 0;
    __syncthreads();

    int t = blockIdx.x * 256 + tid;
    float l[Em];
    float M = -3.0e38f;
#pragma unroll
    for (int i = 0; i < 8; ++i) {
        float4 v = *(const float4*)(logits + (size_t)t * Em + i * 4);
        l[i * 4 + 0] = v.x; l[i * 4 + 1] = v.y;
        l[i * 4 + 2] = v.z; l[i * 4 + 3] = v.w;
        M = fmaxf(M, fmaxf(fmaxf(v.x, v.y), fmaxf(v.z, v.w)));
    }
    float sum = 0.f;
#pragma unroll
    for (int i = 0; i < Em; ++i) sum += __expf(l[i] - M);
    float inv = 1.0f / sum;
#pragma unroll
    for (int k = 0; k < 4; ++k) {
        float best = -3.0e38f; int bi = 0;
#pragma unroll
        for (int i = 0; i < Em; ++i)
            if (l[i] > best) { best = l[i]; bi = i; }
        topk_e[t * 4 + k] = bi;
        topk_w[t * 4 + k] = __expf(best - M) * inv;
        atomicAdd(&hist[bi], 1);
#pragma unroll
        for (int i = 0; i < Em; ++i)
            if (i == bi) l[i] = -3.0e38f;
    }
    __syncthreads();
    if (tid < Em) { int h = hist[tid]; if (h) atomicAdd(&cnt[tid], h); }
}

__global__ void offsets_kernel(const int* __restrict__ cnt, int* __restrict__ cntc,
                               int* __restrict__ offs)
{
    if (threadIdx.x == 0) {
        int run = 0;
        for (int e = 0; e < Em; ++e) {
            int c = cnt[e]; if (c > CAP) c = CAP;
            cntc[e] = c; offs[e] = run; run += c;
        }
        offs[Em] = run;
    }
}

// Also records pair -> compact-row map (posC, -1 = capacity-dropped).
__global__ void scatter_kernel(const int* __restrict__ topk_e, const float* __restrict__ topk_w,
                               const int* __restrict__ cntc, const int* __restrict__ offs,
                               int* __restrict__ cnt2, int* __restrict__ tok_c,
                               float* __restrict__ wt_c, int* __restrict__ posC)
{
    int p = blockIdx.x * 256 + threadIdx.x;
    if (p >= Pp) return;
    int e = topk_e[p];
    int slot = atomicAdd(&cnt2[e], 1);
    int rc = -1;
    if (slot < cntc[e]) {
        rc = offs[e] + slot;
        tok_c[rc] = p >> 2;
        wt_c[rc] = topk_w[p];
    }
    posC[p] = rc;
}

// ---------------------------------------------------------------- casts -----
__global__ void cast_x_kernel(const float* __restrict__ src, bf16* __restrict__ dst, int n4)
{
    int i = blockIdx.x * 256 + threadIdx.x;
    if (i >= n4) return;
    float4 v = ((const float4*)src)[i];
    bf16x4 o = {(bf16)v.x, (bf16)v.y, (bf16)v.z, (bf16)v.w};
    ((bf16x4*)dst)[i] = o;
}

// src: batches of (R x Cc) fp32 row-major -> dst: (Cc x R) bf16 row-major.
__global__ void transpose_cast(const float* __restrict__ src, bf16* __restrict__ dst,
                               int R, int Cc, long sstride, long dstride)
{
    __shared__ float t[32][33];
    int b = blockIdx.z;
    src += (long)b * sstride;
    dst += (long)b * dstride;
    int r0 = blockIdx.y * 32, c0 = blockIdx.x * 32;
    int tx = threadIdx.x, ty = threadIdx.y;
#pragma unroll
    for (int i = 0; i < 4; ++i)
        t[ty + i * 8][tx] = src[(long)(r0 + ty + i * 8) * Cc + (c0 + tx)];
    __syncthreads();
#pragma unroll
    for (int i = 0; i < 4; ++i)
        dst[(long)(c0 + ty + i * 8) * R + (r0 + tx)] = (bf16)t[tx][ty + i * 8];
}

// ---------------------------------------------------------------- GEMM ------
// Shared helpers: 128x128 tile, BK=64, 4 waves (each 64x64),
// mfma_f32_16x16x32_bf16, global_load_lds width-16, XOR-swizzled LDS chunks.
__device__ __forceinline__ void gload_lds16(const bf16* g, bf16* l)
{
    __builtin_amdgcn_global_load_lds((const __attribute__((address_space(1))) void*)g,
                                     (__attribute__((address_space(3))) void*)l, 16, 0, 0);
}

// GEMM1 with fused SwiGLU epilogue: stages A once, both W1- and W3-tiles of
// BT (W1 rows at [0,N), W3 rows at [n3off, n3off+N)), computes
// h = silu(A.W1col) * (A.W3col), stores bf16 compact rows.
template <bool EXPERT>
__global__ void __launch_bounds__(256, 2) gemm1_fused(
    const bf16* __restrict__ A, const bf16* __restrict__ BT,
    int K, int lda, int n3off,
    const int* __restrict__ cntc, const int* __restrict__ offs,
    const int* __restrict__ tok, long strideBT,
    bf16* __restrict__ outH, int ldo, int mtotal)
{
    __shared__ __align__(16) bf16 As[128 * 64];
    __shared__ __align__(16) bf16 B1[128 * 64];
    __shared__ __align__(16) bf16 B3[128 * 64];

    int mt, mcount, rowbase;
    if (EXPERT) {
        int e = blockIdx.y >> 4;          // CAP/128 = 16 m-tiles per expert
        mt = blockIdx.y & 15;
        mcount = cntc[e];
        if (mt * 128 >= mcount) return;
        rowbase = offs[e];
        BT += (long)e * strideBT;
    } else {
        mt = blockIdx.y; mcount = mtotal; rowbase = 0;
    }
    int nt = blockIdx.x;

    int tid = threadIdx.x;
    int wave = tid >> 6, lane = tid & 63;
    int wm = wave >> 1, wn = wave & 1;
    int q = lane >> 4, lm = lane & 15;

    floatx4 acc1[4][4] = {};
    floatx4 acc3[4][4] = {};

    const bf16* arow[4];
    const bf16* brow[4];
    long off3 = (long)n3off * K;
#pragma unroll
    for (int it = 0; it < 4; ++it) {
        int c = wave * 256 + it * 64 + lane;
        int row = c >> 3;
        int kc = (c & 7) ^ (row & 7);      // XOR swizzle on 16B chunks
        int rl = mt * 128 + row;
        int rr = rl < mcount ? rl : mcount - 1;
        long aoff;
        if (EXPERT) aoff = (long)tok[rowbase + rr] * lda;
        else        aoff = (long)rr * lda;
        arow[it] = A + aoff + kc * 8;
        brow[it] = BT + (long)(nt * 128 + row) * K + kc * 8;
    }

    for (int kt = 0; kt < K; kt += 64) {
#pragma unroll
        for (int it = 0; it < 4; ++it)
            gload_lds16(arow[it] + kt, As + (wave * 256 + it * 64) * 8);
#pragma unroll
        for (int it = 0; it < 4; ++it)
            gload_lds16(brow[it] + kt, B1 + (wave * 256 + it * 64) * 8);
#pragma unroll
        for (int it = 0; it < 4; ++it)
            gload_lds16(brow[it] + off3 + kt, B3 + (wave * 256 + it * 64) * 8);
        __syncthreads();
#pragma unroll
        for (int kk = 0; kk < 2; ++kk) {
            bf16x8 af[4], b1v[4], b3v[4];
            int j = kk * 4 + q;
#pragma unroll
            for (int i = 0; i < 4; ++i) {
                int row = wm * 64 + i * 16 + lm;
                af[i] = *(const bf16x8*)(As + row * 64 + ((j ^ (row & 7)) * 8));
            }
#pragma unroll
            for (int j2 = 0; j2 < 4; ++j2) {
                int row = wn * 64 + j2 * 16 + lm;
                b1v[j2] = *(const bf16x8*)(B1 + row * 64 + ((j ^ (row & 7)) * 8));
                b3v[j2] = *(const bf16x8*)(B3 + row * 64 + ((j ^ (row & 7)) * 8));
            }
#pragma unroll
            for (int i = 0; i < 4; ++i)
#pragma unroll
                for (int j2 = 0; j2 < 4; ++j2) {
                    acc1[i][j2] = __builtin_amdgcn_mfma_f32_16x16x32_bf16(
                        af[i], b1v[j2], acc1[i][j2], 0, 0, 0);
                    acc3[i][j2] = __builtin_amdgcn_mfma_f32_16x16x32_bf16(
                        af[i], b3v[j2], acc3[i][j2], 0, 0, 0);
                }
        }
        __syncthreads();
    }

    int colbase = nt * 128 + wn * 64;
#pragma unroll
    for (int i = 0; i < 4; ++i) {
        int rloc = wm * 64 + i * 16 + q * 4;
#pragma unroll
        for (int r = 0; r < 4; ++r) {
            int rl = mt * 128 + rloc + r;
            if (rl >= mcount) continue;
#pragma unroll
            for (int j2 = 0; j2 < 4; ++j2) {
                int col = colbase + j2 * 16 + lm;
                float a = acc1[i][j2][r], b = acc3[i][j2][r];
                float sg = 1.0f / (1.0f + __expf(-a));
                outH[(long)(rowbase + rl) * ldo + col] = (bf16)(a * sg * b);
            }
        }
    }
}

// Plain GEMM: MODE 0 = bf16 compact store, MODE 2 = fp32 plain store.
template <int MODE, bool EXPERT>
__global__ void __launch_bounds__(256, 2) gemm_bt(
    const bf16* __restrict__ A, const bf16* __restrict__ BT,
    int K, int lda,
    const int* __restrict__ cntc, const int* __restrict__ offs,
    long strideBT,
    bf16* __restrict__ outB, float* __restrict__ outF, int ldo, int mtotal)
{
    __shared__ __align__(16) bf16 As[128 * 64];
    __shared__ __align__(16) bf16 Bs[128 * 64];

    int mt, mcount, rowbase;
    if (EXPERT) {
        int e = blockIdx.y >> 4;
        mt = blockIdx.y & 15;
        mcount = cntc[e];
        if (mt * 128 >= mcount) return;
        rowbase = offs[e];
        BT += (long)e * strideBT;
    } else {
        mt = blockIdx.y; mcount = mtotal; rowbase = 0;
    }
    int nt = blockIdx.x;

    int tid = threadIdx.x;
    int wave = tid >> 6, lane = tid & 63;
    int wm = wave >> 1, wn = wave & 1;
    int q = lane >> 4, lm = lane & 15;

    floatx4 acc[4][4] = {};

    const bf16* arow[4];
    const bf16* brow[4];
#pragma unroll
    for (int it = 0; it < 4; ++it) {
        int c = wave * 256 + it * 64 + lane;
        int row = c >> 3;
        int kc = (c & 7) ^ (row & 7);
        int rl = mt * 128 + row;
        int rr = rl < mcount ? rl : mcount - 1;
        arow[it] = A + (long)(rowbase + rr) * lda + kc * 8;
        brow[it] = BT + (long)(nt * 128 + row) * K + kc * 8;
    }

    for (int kt = 0; kt < K; kt += 64) {
#pragma unroll
        for (int it = 0; it < 4; ++it)
            gload_lds16(arow[it] + kt, As + (wave * 256 + it * 64) * 8);
#pragma unroll
        for (int it = 0; it < 4; ++it)
            gload_lds16(brow[it] + kt, Bs + (wave * 256 + it * 64) * 8);
        __syncthreads();
#pragma unroll
        for (int kk = 0; kk < 2; ++kk) {
            bf16x8 af[4], bfv[4];
            int j = kk * 4 + q;
#pragma unroll
            for (int i = 0; i < 4; ++i) {
                int row = wm * 64 + i * 16 + lm;
                af[i] = *(const bf16x8*)(As + row * 64 + ((j ^ (row & 7)) * 8));
            }
#pragma unroll
            for (int j2 = 0; j2 < 4; ++j2) {
                int row = wn * 64 + j2 * 16 + lm;
                bfv[j2] = *(const bf16x8*)(Bs + row * 64 + ((j ^ (row & 7)) * 8));
            }
#pragma unroll
            for (int i = 0; i < 4; ++i)
#pragma unroll
                for (int j2 = 0; j2 < 4; ++j2)
                    acc[i][j2] = __builtin_amdgcn_mfma_f32_16x16x32_bf16(
                        af[i], bfv[j2], acc[i][j2], 0, 0, 0);
        }
        __syncthreads();
    }

    int colbase = nt * 128 + wn * 64;
#pragma unroll
    for (int i = 0; i < 4; ++i) {
        int rloc = wm * 64 + i * 16 + q * 4;
#pragma unroll
        for (int r = 0; r < 4; ++r) {
            int rl = mt * 128 + rloc + r;
            if (rl >= mcount) continue;
#pragma unroll
            for (int j2 = 0; j2 < 4; ++j2) {
                int col = colbase + j2 * 16 + lm;
                float v = acc[i][j2][r];
                if (MODE == 0) outB[(long)(rowbase + rl) * ldo + col] = (bf16)v;
                else           outF[(long)rl * ldo + col] = v;
            }
        }
    }
}

// ------------------------------------------------------------- combine ------
// out[t][:] += sum_k w[t,k] * Yc[posC[t*4+k]][:]  (posC<0 => dropped pair).
// One block per token; out already holds the shared-experts result z.
__global__ __launch_bounds__(256) void combine_kernel(
    const bf16* __restrict__ Yc, const float* __restrict__ topkW,
    const int* __restrict__ posC, float* __restrict__ out)
{
    __shared__ int   sp[4];
    __shared__ float sw[4];
    int t = blockIdx.x, tid = threadIdx.x;
    if (tid < 4) {
        sp[tid] = posC[t * 4 + tid];
        sw[tid] = topkW[t * 4 + tid];
    }
    __syncthreads();
    int d = tid * 4;
    float4 o = *(float4*)(out + (size_t)t * Dm + d);
#pragma unroll
    for (int k = 0; k < 4; ++k) {
        int rc = sp[k];
        if (rc >= 0) {
            bf16x4 v = *(const bf16x4*)(Yc + (size_t)rc * Dm + d);
            float w = sw[k];
            o.x += w * (float)v[0];
            o.y += w * (float)v[1];
            o.z += w * (float)v[2];
            o.w += w * (float)v[3];
        }
    }
    *(float4*)(out + (size_t)t * Dm + d) = o;
}

// ---------------------------------------------------------------- launch ----
extern "C" void kernel_launch(void* const* d_in, const int* in_sizes, int n_in,
                              void* d_out, int out_size, void* d_ws, size_t ws_size,
                              hipStream_t stream)
{
    const float* x   = (const float*)d_in[0];
    const float* Wg  = (const float*)d_in[1];
    const float* W1  = (const float*)d_in[2];
    const float* W2  = (const float*)d_in[3];
    const float* W3  = (const float*)d_in[4];
    const float* Ws1 = (const float*)d_in[5];
    const float* Ws2 = (const float*)d_in[6];
    const float* Ws3 = (const float*)d_in[7];
    float* out = (float*)d_out;

    char* p = (char*)d_ws;
    auto alloc = [&](size_t bytes) {
        char* r = p; p += (bytes + 255) & ~(size_t)255; return r;
    };
    bf16*  xb    = (bf16*)alloc((size_t)T_TOK * Dm * 2);
    bf16*  W13T  = (bf16*)alloc((size_t)Em * 2 * Hm * Dm * 2);
    bf16*  W2T   = (bf16*)alloc((size_t)Em * Dm * Hm * 2);
    bf16*  Ws13T = (bf16*)alloc((size_t)Hs2 * Dm * 2);
    bf16*  Ws2T  = (bf16*)alloc((size_t)Dm * HsDim * 2);
    bf16*  Yc    = (bf16*)alloc((size_t)Pp * Dm * 2);      // expert GEMM2 compact out
    bf16*  Hh    = (bf16*)alloc((size_t)Pp * Hm * 2);      // expert hidden (compact)
    bf16*  HhS   = (bf16*)alloc((size_t)T_TOK * HsDim * 2);// shared hidden
    float* logits= (float*)alloc((size_t)T_TOK * Em * 4);
    int*   topkE = (int*)alloc(Pp * 4);
    float* topkW = (float*)alloc(Pp * 4);
    int*   tokC  = (int*)alloc(Pp * 4);
    float* wtC   = (float*)alloc(Pp * 4);
    int*   posC  = (int*)alloc(Pp * 4);
    int*   cnt   = (int*)alloc(128);
    int*   cnt2  = (int*)alloc(128);
    int*   cntc  = (int*)alloc(128);
    int*   offs  = (int*)alloc(256);

    size_t need = (size_t)(p - (char*)d_ws);
    if (ws_size < need) {
        fprintf(stderr, "kernel_launch: ws too small (%zu < %zu)\n", ws_size, need);
        return;
    }

    hipMemsetAsync(cnt, 0, 1024, stream);  // cnt, cnt2, cntc, offs

    // Routing (fp32, matches reference top-k exactly)
    gate_logits<<<T_TOK / 8, 256, 0, stream>>>(x, Wg, logits);
    gate_topk<<<T_TOK / 256, 256, 0, stream>>>(logits, topkE, topkW, cnt);
    offsets_kernel<<<1, 64, 0, stream>>>(cnt, cntc, offs);
    scatter_kernel<<<Pp / 256, 256, 0, stream>>>(topkE, topkW, cntc, offs, cnt2,
                                                 tokC, wtC, posC);

    // bf16 casts / B^T layouts
    cast_x_kernel<<<(T_TOK * Dm / 4) / 256, 256, 0, stream>>>(x, xb, T_TOK * Dm / 4);
    transpose_cast<<<dim3(Hm / 32, Dm / 32, Em), dim3(32, 8), 0, stream>>>(
        W1, W13T, Dm, Hm, (long)Dm * Hm, (long)2 * Hm * Dm);
    transpose_cast<<<dim3(Hm / 32, Dm / 32, Em), dim3(32, 8), 0, stream>>>(
        W3, W13T + (size_t)Hm * Dm, Dm, Hm, (long)Dm * Hm, (long)2 * Hm * Dm);
    transpose_cast<<<dim3(Dm / 32, Hm / 32, Em), dim3(32, 8), 0, stream>>>(
        W2, W2T, Hm, Dm, (long)Hm * Dm, (long)Hm * Dm);
    transpose_cast<<<dim3(HsDim / 32, Dm / 32, 1), dim3(32, 8), 0, stream>>>(
        Ws1, Ws13T, Dm, HsDim, 0, 0);
    transpose_cast<<<dim3(HsDim / 32, Dm / 32, 1), dim3(32, 8), 0, stream>>>(
        Ws3, Ws13T + (size_t)HsDim * Dm, Dm, HsDim, 0, 0);
    transpose_cast<<<dim3(Dm / 32, HsDim / 32, 1), dim3(32, 8), 0, stream>>>(
        Ws2, Ws2T, HsDim, Dm, 0, 0);

    // Shared experts: fused GEMM1+SwiGLU -> GEMM2 plain-stores z into out.
    gemm1_fused<false><<<dim3(HsDim / 128, T_TOK / 128), 256, 0, stream>>>(
        xb, Ws13T, Dm, Dm, HsDim, nullptr, nullptr, nullptr, 0,
        HhS, HsDim, T_TOK);
    gemm_bt<2, false><<<dim3(Dm / 128, T_TOK / 128), 256, 0, stream>>>(
        HhS, Ws2T, HsDim, HsDim, nullptr, nullptr, 0,
        nullptr, out, Dm, T_TOK);

    // Routed experts: fused gather-GEMM1+SwiGLU -> compact GEMM2 -> combine.
    gemm1_fused<true><<<dim3(Hm / 128, Em * (CAP / 128)), 256, 0, stream>>>(
        xb, W13T, Dm, Dm, Hm, cntc, offs, tokC, (long)2 * Hm * Dm,
        Hh, Hm, 0);
    gemm_bt<0, true><<<dim3(Dm / 128, Em * (CAP / 128)), 256, 0, stream>>>(
        Hh, W2T, Hm, Hm, cntc, offs, (long)Hm * Dm,
        Yc, nullptr, Dm, 0);
    combine_kernel<<<T_TOK, 256, 0, stream>>>(Yc, topkW, posC, out);
}